// Round 6
// baseline (1139.430 us; speedup 1.0000x reference)
//
#include <hip/hip_runtime.h>
#include <hip/hip_bf16.h>

typedef __bf16 bf16;
typedef __bf16 bf16x8 __attribute__((ext_vector_type(8)));
typedef float f32x4 __attribute__((ext_vector_type(4)));
typedef float f32x16 __attribute__((ext_vector_type(16)));

#define D_MODEL 2048
#define D_INNER 4096
#define ROWS    8192   // B*T

__device__ __forceinline__ void gload_lds16(const void* g, void* l) {
    __builtin_amdgcn_global_load_lds(
        (const __attribute__((address_space(1))) void*)g,
        (__attribute__((address_space(3))) void*)l, 16, 0, 0);
}

// ---------------- fp32 -> bf16 weight convert ----------------
__global__ __launch_bounds__(256) void f2b_kernel(const float* __restrict__ in,
                                                  bf16* __restrict__ out, int n8) {
    int i = blockIdx.x * 256 + threadIdx.x;
    if (i >= n8) return;
    long base = (long)i * 8;
    float4 a = *(const float4*)(in + base);
    float4 b = *(const float4*)(in + base + 4);
    bf16x8 o;
    o[0] = (bf16)a.x; o[1] = (bf16)a.y; o[2] = (bf16)a.z; o[3] = (bf16)a.w;
    o[4] = (bf16)b.x; o[5] = (bf16)b.y; o[6] = (bf16)b.z; o[7] = (bf16)b.w;
    *(bf16x8*)(out + base) = o;
}

// ---------------- rmsnorm (F.normalize * sqrt(D)) fp32 -> bf16 ----------------
__global__ __launch_bounds__(256) void rmsnorm_kernel(const float* __restrict__ x,
                                                      bf16* __restrict__ h) {
    const long row = blockIdx.x;
    const float* xr = x + row * D_MODEL;
    float4 v0 = ((const float4*)xr)[threadIdx.x * 2];
    float4 v1 = ((const float4*)xr)[threadIdx.x * 2 + 1];
    float ss = v0.x*v0.x + v0.y*v0.y + v0.z*v0.z + v0.w*v0.w
             + v1.x*v1.x + v1.y*v1.y + v1.z*v1.z + v1.w*v1.w;
    #pragma unroll
    for (int o = 32; o; o >>= 1) ss += __shfl_xor(ss, o, 64);
    __shared__ float red[4];
    if ((threadIdx.x & 63) == 0) red[threadIdx.x >> 6] = ss;
    __syncthreads();
    float tot = red[0] + red[1] + red[2] + red[3];
    float scale = 45.254834f / fmaxf(sqrtf(tot), 1e-12f);  // sqrt(2048)/max(||x||,eps)
    bf16x8 o;
    o[0] = (bf16)(v0.x*scale); o[1] = (bf16)(v0.y*scale);
    o[2] = (bf16)(v0.z*scale); o[3] = (bf16)(v0.w*scale);
    o[4] = (bf16)(v1.x*scale); o[5] = (bf16)(v1.y*scale);
    o[6] = (bf16)(v1.z*scale); o[7] = (bf16)(v1.w*scale);
    *(bf16x8*)(h + row * D_MODEL + threadIdx.x * 8) = o;
}

// ---------------- depthwise causal conv (4 taps) + SiLU gate ----------------
__global__ __launch_bounds__(256) void conv_gate_kernel(bf16* __restrict__ xz,
                                                        const float* __restrict__ cw,
                                                        const float* __restrict__ cb) {
    const int idx = blockIdx.x * 256 + threadIdx.x;   // ROWS*512 threads
    const int c8  = idx & 511;
    const int row = idx >> 9;
    const int t   = row & 2047;                        // position within batch (T=2048)
    const int c0  = c8 * 8;
    float acc[8];
    float wv[8][4];
    #pragma unroll
    for (int e = 0; e < 8; ++e) {
        float4 f = ((const float4*)cw)[c0 + e];
        wv[e][0] = f.x; wv[e][1] = f.y; wv[e][2] = f.z; wv[e][3] = f.w;
        acc[e] = cb[c0 + e];
    }
    #pragma unroll
    for (int j = 0; j < 4; ++j) {
        if (t + j - 3 >= 0) {
            bf16x8 xv = *(const bf16x8*)(xz + (long)(row + j - 3) * (2*D_INNER) + c0);
            #pragma unroll
            for (int e = 0; e < 8; ++e) acc[e] += (float)xv[e] * wv[e][j];
        }
    }
    bf16* zp = xz + (long)row * (2*D_INNER) + D_INNER + c0;
    bf16x8 zv = *(const bf16x8*)zp;
    bf16x8 yv;
    #pragma unroll
    for (int e = 0; e < 8; ++e) {
        float xc = acc[e];
        float s1 = xc / (1.f + __expf(-xc));
        float z  = (float)zv[e];
        float s2 = z / (1.f + __expf(-z));
        yv[e] = (bf16)(s1 * s2);
    }
    *(bf16x8*)zp = yv;
}

// ---------------- bf16 GEMM v6 (32x32x16 MFMA): C = A @ B^T ----------------
// 256x256 tile, BK=64, 512 threads = 8 waves (2M x 4N), per-wave 128x64 =
// 4 m-blocks x 2 n-blocks of 32x32; K-tile = 4 k-steps of 16.
// v5's pipeline kept verbatim (2 dbuf x 64KB, XOR chunk swizzle with
// inverse-swizzled global source, 2 super-phases/K-tile, counted vmcnt):
//   P_A(t): stageB(t+2) | q2=A0xBH | vmcnt(4) | read A1->AX | lgkm |
//           q3=A1xBH | barrier
//   P_B(t): q4=A1xBL | stageA(t+2) | read A0,B0,B1(t+1) from other dbuf |
//           lgkm | q1(t+1)=A0xBL | barrier      (q1 skipped on last tile)
// Fragment maps (32x32x16): A/B row = lane&31, k = (lane>>5)*8 + e
// (contiguous bf16x8 -> ds_read_b128); C/D col = lane&31,
// row = (reg&3) + 8*(reg>>2) + 4*(lane>>5). row&7 == lane&7 for all frag
// rows (32 | m-block stride), so the swizzle XOR stays (chunk ^ (l&7)).
// EPI: 0 = store bf16, 1 = relu+store bf16, 2 = fp32 res-add + store fp32
template<int EPI>
__global__ __launch_bounds__(512, 2) void gemm_bt(
        const bf16* __restrict__ A, long lda,
        const bf16* __restrict__ B,
        void* __restrict__ C, const float* __restrict__ res,
        int N, int K, int gx) {
    __shared__ __align__(16) char LB[131072];
    const int tid = threadIdx.x;
    const int w   = tid >> 6;
    const int l   = tid & 63;

    // bijective XCD swizzle (all grids %8 == 0)
    const int nwg = gridDim.x;
    const int qq  = nwg >> 3;
    const int sw  = (blockIdx.x & 7) * qq + (blockIdx.x >> 3);
    const int bx  = sw % gx, by = sw / gx;
    const long rowBase = (long)by * 256;
    const long colBase = (long)bx * 256;

    // staging sources: thread covers row (w*8 + l>>3), 16B chunk (l&7)^((l>>3)&7)
    const int srow = w * 8 + (l >> 3);
    const int schk = (l & 7) ^ ((l >> 3) & 7);
    const bf16* aSrc = A + (rowBase + srow) * lda + schk * 8;
    const bf16* bSrc = B + (colBase + srow) * (long)K + schk * 8;
    const long lda64 = 64 * lda;
    const long ldb64 = 64 * (long)K;
    const int  w1024 = w * 1024;

    auto stgA = [&](int DBB, int kt) {   // A halves -> dbuf DBB (4 loads)
        const bf16* s = aSrc + (long)kt * 64;
        gload_lds16(s,            LB + DBB +     0 + w1024);
        gload_lds16(s +   lda64,  LB + DBB +  8192 + w1024);
        gload_lds16(s + 2*lda64,  LB + DBB + 16384 + w1024);
        gload_lds16(s + 3*lda64,  LB + DBB + 24576 + w1024);
    };
    auto stgB = [&](int DBB, int kt) {   // B halves -> dbuf DBB (4 loads)
        const bf16* s = bSrc + (long)kt * 64;
        gload_lds16(s,            LB + DBB + 32768 + w1024);
        gload_lds16(s +   ldb64,  LB + DBB + 40960 + w1024);
        gload_lds16(s + 2*ldb64,  LB + DBB + 49152 + w1024);
        gload_lds16(s + 3*ldb64,  LB + DBB + 57344 + w1024);
    };

    // fragment read offsets (swizzled); row&7 == l&7 for all frag rows
    const int hm = w >> 2;     // A half (M)
    const int q  = w & 3;      // B quarter (N)
    const int lc = l & 31;     // fragment row-within-block / output col
    int aBase[4], bBase[2], cxk[4];
    #pragma unroll
    for (int mb = 0; mb < 4; ++mb)
        aBase[mb] = hm * 16384 + (mb * 32 + lc) * 128;
    #pragma unroll
    for (int nb = 0; nb < 2; ++nb)
        bBase[nb] = 32768 + (q >> 1) * 16384 + ((q & 1) * 64 + nb * 32 + lc) * 128;
    #pragma unroll
    for (int ks = 0; ks < 4; ++ks)
        cxk[ks] = ((ks * 2 + (l >> 5)) ^ (l & 7)) << 4;

    const int nt  = K >> 6;
    const int nit = nt >> 1;
    f32x16 acc[4][2] = {};
    bf16x8 AX[2][4], BL[4], BH[4];   // AX: [mb-in-half][ks]; B: [ks]

    // prologue: stage tile0 -> dbuf0, tile1 -> dbuf1 (B then A per tile)
    stgB(0, 0);      stgA(0, 0);
    stgB(65536, 1);  stgA(65536, 1);
    asm volatile("s_waitcnt vmcnt(8)" ::: "memory");   // tile 0 landed
    __builtin_amdgcn_s_barrier();
    __builtin_amdgcn_sched_barrier(0);
    // read tile0 q1-frags: AX=A0 (mb0,1), BL=B(nb0), BH=B(nb1)
    #pragma unroll
    for (int ks = 0; ks < 4; ++ks) {
        AX[0][ks] = *(const bf16x8*)(LB + aBase[0] + cxk[ks]);
        AX[1][ks] = *(const bf16x8*)(LB + aBase[1] + cxk[ks]);
        BL[ks]    = *(const bf16x8*)(LB + bBase[0] + cxk[ks]);
        BH[ks]    = *(const bf16x8*)(LB + bBase[1] + cxk[ks]);
    }
    asm volatile("s_waitcnt lgkmcnt(0)" ::: "memory");
    __builtin_amdgcn_sched_barrier(0);
    __builtin_amdgcn_s_setprio(1);
    #pragma unroll
    for (int ks = 0; ks < 4; ++ks)
        #pragma unroll
        for (int mb = 0; mb < 2; ++mb)
            acc[mb][0] = __builtin_amdgcn_mfma_f32_32x32x16_bf16(AX[mb][ks], BL[ks], acc[mb][0], 0, 0, 0);
    __builtin_amdgcn_s_setprio(0);
    __builtin_amdgcn_s_barrier();

    for (int it = 0; it < nit; ++it) {
        int kA = 2 * it + 2; if (kA >= nt) kA = 0;     // dummy clamp in tail
        int kB = 2 * it + 3; if (kB >= nt) kB = 0;
        #pragma unroll
        for (int db = 0; db < 2; ++db) {
            const int DBB = db * 65536;
            const char* Lb = LB + DBB;
            const char* Ln = LB + (DBB ^ 65536);
            const int kst = db ? kB : kA;
            const bool full = (db == 0) || (it < nit - 1);

            // ================= P_A =================
            stgB(DBB, kst);
            __builtin_amdgcn_s_setprio(1);
            #pragma unroll
            for (int ks = 0; ks < 4; ++ks)                   // q2: A0 x BH
                #pragma unroll
                for (int mb = 0; mb < 2; ++mb)
                    acc[mb][1] = __builtin_amdgcn_mfma_f32_32x32x16_bf16(AX[mb][ks], BH[ks], acc[mb][1], 0, 0, 0);
            __builtin_amdgcn_s_setprio(0);
            asm volatile("s_waitcnt vmcnt(4)" ::: "memory");   // t+1 landed (FIFO)
            __builtin_amdgcn_sched_barrier(0);
            #pragma unroll
            for (int ks = 0; ks < 4; ++ks) {                   // AX <- A1(t): mb2,3
                AX[0][ks] = *(const bf16x8*)(Lb + aBase[2] + cxk[ks]);
                AX[1][ks] = *(const bf16x8*)(Lb + aBase[3] + cxk[ks]);
            }
            asm volatile("s_waitcnt lgkmcnt(0)" ::: "memory");
            __builtin_amdgcn_sched_barrier(0);
            __builtin_amdgcn_s_setprio(1);
            #pragma unroll
            for (int ks = 0; ks < 4; ++ks)                   // q3: A1 x BH
                #pragma unroll
                for (int mb = 0; mb < 2; ++mb)
                    acc[mb + 2][1] = __builtin_amdgcn_mfma_f32_32x32x16_bf16(AX[mb][ks], BH[ks], acc[mb + 2][1], 0, 0, 0);
            __builtin_amdgcn_s_setprio(0);
            __builtin_amdgcn_s_barrier();

            // ================= P_B =================
            __builtin_amdgcn_s_setprio(1);
            #pragma unroll
            for (int ks = 0; ks < 4; ++ks)                   // q4: A1 x BL(old)
                #pragma unroll
                for (int mb = 0; mb < 2; ++mb)
                    acc[mb + 2][0] = __builtin_amdgcn_mfma_f32_32x32x16_bf16(AX[mb][ks], BL[ks], acc[mb + 2][0], 0, 0, 0);
            __builtin_amdgcn_s_setprio(0);
            __builtin_amdgcn_sched_barrier(0);
            stgA(DBB, kst);
            if (full) {
                // read next tile's q1-frags from the other dbuf
                #pragma unroll
                for (int ks = 0; ks < 4; ++ks) {
                    AX[0][ks] = *(const bf16x8*)(Ln + aBase[0] + cxk[ks]);
                    AX[1][ks] = *(const bf16x8*)(Ln + aBase[1] + cxk[ks]);
                    BL[ks]    = *(const bf16x8*)(Ln + bBase[0] + cxk[ks]);
                    BH[ks]    = *(const bf16x8*)(Ln + bBase[1] + cxk[ks]);
                }
                asm volatile("s_waitcnt lgkmcnt(0)" ::: "memory");
                __builtin_amdgcn_sched_barrier(0);
                __builtin_amdgcn_s_setprio(1);
                #pragma unroll
                for (int ks = 0; ks < 4; ++ks)               // q1(t+1): A0 x BL
                    #pragma unroll
                    for (int mb = 0; mb < 2; ++mb)
                        acc[mb][0] = __builtin_amdgcn_mfma_f32_32x32x16_bf16(AX[mb][ks], BL[ks], acc[mb][0], 0, 0, 0);
                __builtin_amdgcn_s_setprio(0);
            }
            __builtin_amdgcn_s_barrier();
        }
    }

    // drain dummy prefetch DMAs before the block can exit
    asm volatile("s_waitcnt vmcnt(0)" ::: "memory");

    // epilogue: C/D col = lane&31, row = (reg&3) + 8*(reg>>2) + 4*(lane>>5)
    const int lg5 = (l >> 5) * 4;
    const long wrow = rowBase + hm * 128;
    const long wcol = colBase + q * 64;
    #pragma unroll
    for (int mb = 0; mb < 4; ++mb) {
        #pragma unroll
        for (int nb = 0; nb < 2; ++nb) {
            f32x16 v = acc[mb][nb];
            #pragma unroll
            for (int r = 0; r < 16; ++r) {
                long row = wrow + mb*32 + (r & 3) + 8*(r >> 2) + lg5;
                long col = wcol + nb*32 + lc;
                long off = row * N + col;
                if (EPI == 0)      ((bf16*)C)[off] = (bf16)v[r];
                else if (EPI == 1) ((bf16*)C)[off] = (bf16)fmaxf(v[r], 0.f);
                else               ((float*)C)[off] = res[off] + v[r];
            }
        }
    }
}

extern "C" void kernel_launch(void* const* d_in, const int* in_sizes, int n_in,
                              void* d_out, int out_size, void* d_ws, size_t ws_size,
                              hipStream_t stream) {
    const float* x      = (const float*)d_in[0];
    const float* W_in   = (const float*)d_in[1];
    const float* cw     = (const float*)d_in[2];
    const float* cb     = (const float*)d_in[3];
    const float* W_out  = (const float*)d_in[4];
    const float* W_mlp1 = (const float*)d_in[5];
    const float* W_mlp2 = (const float*)d_in[6];
    float* out = (float*)d_out;

    char* ws  = (char*)d_ws;
    bf16* wW  = (bf16*)(ws);                    // 33.55 MB (max bf16 weight)
    bf16* h   = (bf16*)(ws + 33554432);         // 33.55 MB (h / h2)
    bf16* xz  = (bf16*)(ws + 67108864);         // 134.2 MB (xz / m1)
    float* x2 = (float*)(ws + 201326592);       // 67.1 MB
    bf16* y   = xz + D_INNER;                   // in-place over z half, lda = 8192
    bf16* m1  = xz;

    dim3 blk(256);
    dim3 gblk(512);

    // mamba branch
    f2b_kernel<<<dim3(8192), blk, 0, stream>>>(W_in, wW, 16777216/8);
    rmsnorm_kernel<<<dim3(ROWS), blk, 0, stream>>>(x, h);
    gemm_bt<0><<<dim3(1024), gblk, 0, stream>>>(h, D_MODEL, wW, xz, nullptr, 2*D_INNER, D_MODEL, 32);
    conv_gate_kernel<<<dim3(16384), blk, 0, stream>>>(xz, cw, cb);
    f2b_kernel<<<dim3(4096), blk, 0, stream>>>(W_out, wW, 8388608/8);
    gemm_bt<2><<<dim3(256), gblk, 0, stream>>>(y, 2*D_INNER, wW, x2, x, D_MODEL, D_INNER, 8);

    // mlp branch
    rmsnorm_kernel<<<dim3(ROWS), blk, 0, stream>>>(x2, h);
    f2b_kernel<<<dim3(8192), blk, 0, stream>>>(W_mlp1, wW, 16777216/8);
    gemm_bt<1><<<dim3(1024), gblk, 0, stream>>>(h, D_MODEL, wW, m1, nullptr, 4*D_MODEL, D_MODEL, 32);
    f2b_kernel<<<dim3(8192), blk, 0, stream>>>(W_mlp2, wW, 16777216/8);
    gemm_bt<2><<<dim3(256), gblk, 0, stream>>>(m1, 4*D_MODEL, wW, out, x2, D_MODEL, 4*D_MODEL, 8);
}

// Round 7
// 1003.157 us; speedup vs baseline: 1.1358x; 1.1358x over previous
//
#include <hip/hip_runtime.h>
#include <hip/hip_bf16.h>

typedef __bf16 bf16;
typedef __bf16 bf16x8 __attribute__((ext_vector_type(8)));
typedef float f32x4 __attribute__((ext_vector_type(4)));

#define D_MODEL 2048
#define D_INNER 4096
#define ROWS    8192   // B*T

__device__ __forceinline__ void gload_lds16(const void* g, void* l) {
    __builtin_amdgcn_global_load_lds(
        (const __attribute__((address_space(1))) void*)g,
        (__attribute__((address_space(3))) void*)l, 16, 0, 0);
}

// ---------------- fp32 -> bf16 weight convert ----------------
__global__ __launch_bounds__(256) void f2b_kernel(const float* __restrict__ in,
                                                  bf16* __restrict__ out, int n8) {
    int i = blockIdx.x * 256 + threadIdx.x;
    if (i >= n8) return;
    long base = (long)i * 8;
    float4 a = *(const float4*)(in + base);
    float4 b = *(const float4*)(in + base + 4);
    bf16x8 o;
    o[0] = (bf16)a.x; o[1] = (bf16)a.y; o[2] = (bf16)a.z; o[3] = (bf16)a.w;
    o[4] = (bf16)b.x; o[5] = (bf16)b.y; o[6] = (bf16)b.z; o[7] = (bf16)b.w;
    *(bf16x8*)(out + base) = o;
}

// ---------------- rmsnorm (F.normalize * sqrt(D)) fp32 -> bf16 ----------------
__global__ __launch_bounds__(256) void rmsnorm_kernel(const float* __restrict__ x,
                                                      bf16* __restrict__ h) {
    const long row = blockIdx.x;
    const float* xr = x + row * D_MODEL;
    float4 v0 = ((const float4*)xr)[threadIdx.x * 2];
    float4 v1 = ((const float4*)xr)[threadIdx.x * 2 + 1];
    float ss = v0.x*v0.x + v0.y*v0.y + v0.z*v0.z + v0.w*v0.w
             + v1.x*v1.x + v1.y*v1.y + v1.z*v1.z + v1.w*v1.w;
    #pragma unroll
    for (int o = 32; o; o >>= 1) ss += __shfl_xor(ss, o, 64);
    __shared__ float red[4];
    if ((threadIdx.x & 63) == 0) red[threadIdx.x >> 6] = ss;
    __syncthreads();
    float tot = red[0] + red[1] + red[2] + red[3];
    float scale = 45.254834f / fmaxf(sqrtf(tot), 1e-12f);  // sqrt(2048)/max(||x||,eps)
    bf16x8 o;
    o[0] = (bf16)(v0.x*scale); o[1] = (bf16)(v0.y*scale);
    o[2] = (bf16)(v0.z*scale); o[3] = (bf16)(v0.w*scale);
    o[4] = (bf16)(v1.x*scale); o[5] = (bf16)(v1.y*scale);
    o[6] = (bf16)(v1.z*scale); o[7] = (bf16)(v1.w*scale);
    *(bf16x8*)(h + row * D_MODEL + threadIdx.x * 8) = o;
}

// ---------------- depthwise causal conv (4 taps) + SiLU gate ----------------
__global__ __launch_bounds__(256) void conv_gate_kernel(bf16* __restrict__ xz,
                                                        const float* __restrict__ cw,
                                                        const float* __restrict__ cb) {
    const int idx = blockIdx.x * 256 + threadIdx.x;   // ROWS*512 threads
    const int c8  = idx & 511;
    const int row = idx >> 9;
    const int t   = row & 2047;                        // position within batch (T=2048)
    const int c0  = c8 * 8;
    float acc[8];
    float wv[8][4];
    #pragma unroll
    for (int e = 0; e < 8; ++e) {
        float4 f = ((const float4*)cw)[c0 + e];
        wv[e][0] = f.x; wv[e][1] = f.y; wv[e][2] = f.z; wv[e][3] = f.w;
        acc[e] = cb[c0 + e];
    }
    #pragma unroll
    for (int j = 0; j < 4; ++j) {
        if (t + j - 3 >= 0) {
            bf16x8 xv = *(const bf16x8*)(xz + (long)(row + j - 3) * (2*D_INNER) + c0);
            #pragma unroll
            for (int e = 0; e < 8; ++e) acc[e] += (float)xv[e] * wv[e][j];
        }
    }
    bf16* zp = xz + (long)row * (2*D_INNER) + D_INNER + c0;
    bf16x8 zv = *(const bf16x8*)zp;
    bf16x8 yv;
    #pragma unroll
    for (int e = 0; e < 8; ++e) {
        float xc = acc[e];
        float s1 = xc / (1.f + __expf(-xc));
        float z  = (float)zv[e];
        float s2 = z / (1.f + __expf(-z));
        yv[e] = (bf16)(s1 * s2);
    }
    *(bf16x8*)zp = yv;
}

// ---------------- bf16 GEMM v7 (= v5 core + LDS-vectorized epilogue) ----------
// 256x256 tile, BK=64, 512 threads = 8 waves (2M x 4N), per-wave 128x64.
// K-loop identical to v5 (proven 51% MfmaUtil): 2 dbuf x 64KB, XOR chunk
// swizzle with inverse-swizzled global source, 2 super-phases/K-tile,
// counted vmcnt, q1 waits lgkmcnt(4) (BH reordered last, lands under q1).
// NEW epilogue: after vmcnt(0)+barrier the 128KB LDS is dead; each wave
// writes its acc into a private 16KB region (chunk-XOR swizzled, <=2-way
// free) and reads back b128 -> global_store_dwordx4 (coalesced 128B rows).
// EPI=2 (fp32 out) runs two 64-row passes with float4 res loads.
// EPI: 0 = store bf16, 1 = relu+store bf16, 2 = fp32 res-add + store fp32
template<int EPI>
__global__ __launch_bounds__(512, 2) void gemm_bt(
        const bf16* __restrict__ A, long lda,
        const bf16* __restrict__ B,
        void* __restrict__ C, const float* __restrict__ res,
        int N, int K, int gx) {
    __shared__ __align__(16) char LB[131072];
    const int tid = threadIdx.x;
    const int w   = tid >> 6;
    const int l   = tid & 63;
    const int lr  = l & 15;

    // bijective XCD swizzle (all grids %8 == 0)
    const int nwg = gridDim.x;
    const int qq  = nwg >> 3;
    const int sw  = (blockIdx.x & 7) * qq + (blockIdx.x >> 3);
    const int bx  = sw % gx, by = sw / gx;
    const long rowBase = (long)by * 256;
    const long colBase = (long)bx * 256;

    // staging sources: thread covers row (w*8 + l>>3), 16B chunk (l&7)^((l>>3)&7)
    const int srow = w * 8 + (l >> 3);
    const int schk = (l & 7) ^ ((l >> 3) & 7);
    const bf16* aSrc = A + (rowBase + srow) * lda + schk * 8;
    const bf16* bSrc = B + (colBase + srow) * (long)K + schk * 8;
    const long lda64 = 64 * lda;
    const long ldb64 = 64 * (long)K;
    const int  w1024 = w * 1024;

    auto stgA = [&](int DBB, int kt) {   // A halves -> dbuf DBB (4 loads)
        const bf16* s = aSrc + (long)kt * 64;
        gload_lds16(s,            LB + DBB +     0 + w1024);
        gload_lds16(s +   lda64,  LB + DBB +  8192 + w1024);
        gload_lds16(s + 2*lda64,  LB + DBB + 16384 + w1024);
        gload_lds16(s + 3*lda64,  LB + DBB + 24576 + w1024);
    };
    auto stgB = [&](int DBB, int kt) {   // B halves -> dbuf DBB (4 loads)
        const bf16* s = bSrc + (long)kt * 64;
        gload_lds16(s,            LB + DBB + 32768 + w1024);
        gload_lds16(s +   ldb64,  LB + DBB + 40960 + w1024);
        gload_lds16(s + 2*ldb64,  LB + DBB + 49152 + w1024);
        gload_lds16(s + 3*ldb64,  LB + DBB + 57344 + w1024);
    };

    // fragment read offsets (swizzled); row&7 == l&7 for all frag rows
    const int cx0 = (((l >> 4)    ) ^ (l & 7)) << 4;
    const int cx1 = (((l >> 4) + 4) ^ (l & 7)) << 4;
    const int hm = w >> 2;     // A half (M)
    const int q  = w & 3;      // B quarter (N)
    int aRow[8], bRow[4];
    #pragma unroll
    for (int m = 0; m < 8; ++m) aRow[m] = hm * 16384 + (m * 16 + lr) * 128;
    #pragma unroll
    for (int n = 0; n < 4; ++n)
        bRow[n] = 32768 + (q >> 1) * 16384 + ((q & 1) * 64 + n * 16 + lr) * 128;

    const int nt  = K >> 6;
    const int nit = nt >> 1;
    f32x4 acc[8][4] = {};
    bf16x8 AX[4][2], BL[2][2], BH[2][2];

    // prologue: stage tile0 -> dbuf0, tile1 -> dbuf1 (B then A per tile)
    stgB(0, 0);      stgA(0, 0);
    stgB(65536, 1);  stgA(65536, 1);
    asm volatile("s_waitcnt vmcnt(8)" ::: "memory");   // tile 0 landed
    __builtin_amdgcn_s_barrier();
    __builtin_amdgcn_sched_barrier(0);
    // read tile0 q1-frags: AX=A0, BL=B0, then BH=B1 last
    #pragma unroll
    for (int m = 0; m < 4; ++m) {
        AX[m][0] = *(const bf16x8*)(LB + aRow[m] + cx0);
        AX[m][1] = *(const bf16x8*)(LB + aRow[m] + cx1);
    }
    #pragma unroll
    for (int n = 0; n < 2; ++n) {
        BL[n][0] = *(const bf16x8*)(LB + bRow[n]     + cx0);
        BL[n][1] = *(const bf16x8*)(LB + bRow[n]     + cx1);
    }
    #pragma unroll
    for (int n = 0; n < 2; ++n) {
        BH[n][0] = *(const bf16x8*)(LB + bRow[n + 2] + cx0);
        BH[n][1] = *(const bf16x8*)(LB + bRow[n + 2] + cx1);
    }
    asm volatile("s_waitcnt lgkmcnt(4)" ::: "memory");
    __builtin_amdgcn_sched_barrier(0);
    __builtin_amdgcn_s_setprio(1);
    #pragma unroll
    for (int m = 0; m < 4; ++m)
        #pragma unroll
        for (int n = 0; n < 2; ++n) {
            acc[m][n] = __builtin_amdgcn_mfma_f32_16x16x32_bf16(AX[m][0], BL[n][0], acc[m][n], 0, 0, 0);
            acc[m][n] = __builtin_amdgcn_mfma_f32_16x16x32_bf16(AX[m][1], BL[n][1], acc[m][n], 0, 0, 0);
        }
    __builtin_amdgcn_s_setprio(0);
    __builtin_amdgcn_s_barrier();

    for (int it = 0; it < nit; ++it) {
        int kA = 2 * it + 2; if (kA >= nt) kA = 0;     // dummy clamp in tail
        int kB = 2 * it + 3; if (kB >= nt) kB = 0;
        #pragma unroll
        for (int db = 0; db < 2; ++db) {
            const int DBB = db * 65536;
            const char* Lb = LB + DBB;
            const char* Ln = LB + (DBB ^ 65536);
            const int kst = db ? kB : kA;
            const bool full = (db == 0) || (it < nit - 1);

            // ================= P_A =================
            stgB(DBB, kst);
            __builtin_amdgcn_s_setprio(1);
            #pragma unroll
            for (int m = 0; m < 4; ++m)                       // q2: A0 x B1
                #pragma unroll
                for (int n = 0; n < 2; ++n) {
                    acc[m][n + 2] = __builtin_amdgcn_mfma_f32_16x16x32_bf16(AX[m][0], BH[n][0], acc[m][n + 2], 0, 0, 0);
                    acc[m][n + 2] = __builtin_amdgcn_mfma_f32_16x16x32_bf16(AX[m][1], BH[n][1], acc[m][n + 2], 0, 0, 0);
                }
            __builtin_amdgcn_s_setprio(0);
            asm volatile("s_waitcnt vmcnt(4)" ::: "memory");   // t+1 landed (FIFO)
            __builtin_amdgcn_sched_barrier(0);
            #pragma unroll
            for (int m = 0; m < 4; ++m) {                      // AX <- A1(t)
                AX[m][0] = *(const bf16x8*)(Lb + aRow[m + 4] + cx0);
                AX[m][1] = *(const bf16x8*)(Lb + aRow[m + 4] + cx1);
            }
            asm volatile("s_waitcnt lgkmcnt(0)" ::: "memory");
            __builtin_amdgcn_sched_barrier(0);
            __builtin_amdgcn_s_setprio(1);
            #pragma unroll
            for (int m = 0; m < 4; ++m)                       // q3: A1 x B1
                #pragma unroll
                for (int n = 0; n < 2; ++n) {
                    acc[m + 4][n + 2] = __builtin_amdgcn_mfma_f32_16x16x32_bf16(AX[m][0], BH[n][0], acc[m + 4][n + 2], 0, 0, 0);
                    acc[m + 4][n + 2] = __builtin_amdgcn_mfma_f32_16x16x32_bf16(AX[m][1], BH[n][1], acc[m + 4][n + 2], 0, 0, 0);
                }
            __builtin_amdgcn_s_setprio(0);
            __builtin_amdgcn_s_barrier();

            // ================= P_B =================
            __builtin_amdgcn_s_setprio(1);
            #pragma unroll
            for (int m = 0; m < 4; ++m)                       // q4: A1 x B0(old)
                #pragma unroll
                for (int n = 0; n < 2; ++n) {
                    acc[m + 4][n] = __builtin_amdgcn_mfma_f32_16x16x32_bf16(AX[m][0], BL[n][0], acc[m + 4][n], 0, 0, 0);
                    acc[m + 4][n] = __builtin_amdgcn_mfma_f32_16x16x32_bf16(AX[m][1], BL[n][1], acc[m + 4][n], 0, 0, 0);
                }
            __builtin_amdgcn_s_setprio(0);
            __builtin_amdgcn_sched_barrier(0);
            stgA(DBB, kst);
            if (full) {
                // read next tile's q1-frags from the other dbuf: AX, BL, BH last
                #pragma unroll
                for (int m = 0; m < 4; ++m) {                  // AX <- A0(t+1)
                    AX[m][0] = *(const bf16x8*)(Ln + aRow[m] + cx0);
                    AX[m][1] = *(const bf16x8*)(Ln + aRow[m] + cx1);
                }
                #pragma unroll
                for (int n = 0; n < 2; ++n) {                  // BL <- B0(t+1)
                    BL[n][0] = *(const bf16x8*)(Ln + bRow[n]     + cx0);
                    BL[n][1] = *(const bf16x8*)(Ln + bRow[n]     + cx1);
                }
                #pragma unroll
                for (int n = 0; n < 2; ++n) {                  // BH <- B1(t+1)
                    BH[n][0] = *(const bf16x8*)(Ln + bRow[n + 2] + cx0);
                    BH[n][1] = *(const bf16x8*)(Ln + bRow[n + 2] + cx1);
                }
                asm volatile("s_waitcnt lgkmcnt(4)" ::: "memory");  // BH lands under q1
                __builtin_amdgcn_sched_barrier(0);
                __builtin_amdgcn_s_setprio(1);
                #pragma unroll
                for (int m = 0; m < 4; ++m)                   // q1(t+1): A0 x B0
                    #pragma unroll
                    for (int n = 0; n < 2; ++n) {
                        acc[m][n] = __builtin_amdgcn_mfma_f32_16x16x32_bf16(AX[m][0], BL[n][0], acc[m][n], 0, 0, 0);
                        acc[m][n] = __builtin_amdgcn_mfma_f32_16x16x32_bf16(AX[m][1], BL[n][1], acc[m][n], 0, 0, 0);
                    }
                __builtin_amdgcn_s_setprio(0);
            }
            __builtin_amdgcn_s_barrier();
        }
    }

    // drain all DMAs (incl. dummy tail prefetches), then barrier: after this
    // no wave has LDS writes in flight -> safe to reuse LB for the epilogue.
    asm volatile("s_waitcnt vmcnt(0)" ::: "memory");
    __builtin_amdgcn_s_barrier();

    // epilogue: C/D layout col = lane&15, row = (lane>>4)*4 + reg.
    // Per-wave private 16KB LDS region, chunk-XOR swizzle (2-way free).
    const int lg = l >> 4;
    const long wrow = rowBase + hm * 128;
    const long wcol = colBase + q * 64;
    char* ep = LB + w * 16384;

    if (EPI == 2) {
        // two passes of 64 rows: [64][64 f32], row stride 256B, 16 chunks
        #pragma unroll
        for (int mh = 0; mh < 2; ++mh) {
            #pragma unroll
            for (int m = 0; m < 4; ++m) {
                #pragma unroll
                for (int n = 0; n < 4; ++n) {
                    f32x4 v = acc[mh * 4 + m][n];
                    #pragma unroll
                    for (int r = 0; r < 4; ++r) {
                        int rowr = m * 16 + lg * 4 + r;
                        int chnk = (n * 4 + (lr >> 2)) ^ (rowr & 7);
                        *(float*)(ep + rowr * 256 + chnk * 16 + (lr & 3) * 4) = v[r];
                    }
                }
            }
            asm volatile("s_waitcnt lgkmcnt(0)" ::: "memory");
            #pragma unroll
            for (int i = 0; i < 16; ++i) {
                int rr = i * 4 + (l >> 4);
                float4 lv = *(float4*)(ep + rr * 256 + (((l & 15) ^ (rr & 7)) * 16));
                long off = (wrow + mh * 64 + rr) * N + wcol + (l & 15) * 4;
                float4 rv = *(const float4*)(res + off);
                lv.x += rv.x; lv.y += rv.y; lv.z += rv.z; lv.w += rv.w;
                *(float4*)((float*)C + off) = lv;
            }
            if (mh == 0) { asm volatile("s_waitcnt lgkmcnt(0) vmcnt(0)" ::: "memory"); }
        }
    } else {
        // [128][64 bf16], row stride 128B, 8 chunks
        #pragma unroll
        for (int m = 0; m < 8; ++m) {
            #pragma unroll
            for (int n = 0; n < 4; ++n) {
                f32x4 v = acc[m][n];
                #pragma unroll
                for (int r = 0; r < 4; ++r) {
                    int rowr = m * 16 + lg * 4 + r;
                    int chnk = (n * 2 + (lr >> 3)) ^ (rowr & 7);
                    float val = (EPI == 1) ? fmaxf(v[r], 0.f) : v[r];
                    *(bf16*)(ep + rowr * 128 + chnk * 16 + (lr & 7) * 2) = (bf16)val;
                }
            }
        }
        asm volatile("s_waitcnt lgkmcnt(0)" ::: "memory");
        #pragma unroll
        for (int i = 0; i < 16; ++i) {
            int rr = i * 8 + (l >> 3);
            uint4 lv = *(uint4*)(ep + rr * 128 + (((l & 7) ^ (rr & 7)) * 16));
            *(uint4*)((bf16*)C + (wrow + rr) * N + wcol + (l & 7) * 8) = lv;
        }
    }
}

extern "C" void kernel_launch(void* const* d_in, const int* in_sizes, int n_in,
                              void* d_out, int out_size, void* d_ws, size_t ws_size,
                              hipStream_t stream) {
    const float* x      = (const float*)d_in[0];
    const float* W_in   = (const float*)d_in[1];
    const float* cw     = (const float*)d_in[2];
    const float* cb     = (const float*)d_in[3];
    const float* W_out  = (const float*)d_in[4];
    const float* W_mlp1 = (const float*)d_in[5];
    const float* W_mlp2 = (const float*)d_in[6];
    float* out = (float*)d_out;

    char* ws  = (char*)d_ws;
    bf16* wW  = (bf16*)(ws);                    // 33.55 MB (max bf16 weight)
    bf16* h   = (bf16*)(ws + 33554432);         // 33.55 MB (h / h2)
    bf16* xz  = (bf16*)(ws + 67108864);         // 134.2 MB (xz / m1)
    float* x2 = (float*)(ws + 201326592);       // 67.1 MB
    bf16* y   = xz + D_INNER;                   // in-place over z half, lda = 8192
    bf16* m1  = xz;

    dim3 blk(256);
    dim3 gblk(512);

    // mamba branch
    f2b_kernel<<<dim3(8192), blk, 0, stream>>>(W_in, wW, 16777216/8);
    rmsnorm_kernel<<<dim3(ROWS), blk, 0, stream>>>(x, h);
    gemm_bt<0><<<dim3(1024), gblk, 0, stream>>>(h, D_MODEL, wW, xz, nullptr, 2*D_INNER, D_MODEL, 32);
    conv_gate_kernel<<<dim3(16384), blk, 0, stream>>>(xz, cw, cb);
    f2b_kernel<<<dim3(4096), blk, 0, stream>>>(W_out, wW, 8388608/8);
    gemm_bt<2><<<dim3(256), gblk, 0, stream>>>(y, 2*D_INNER, wW, x2, x, D_MODEL, D_INNER, 8);

    // mlp branch
    rmsnorm_kernel<<<dim3(ROWS), blk, 0, stream>>>(x2, h);
    f2b_kernel<<<dim3(8192), blk, 0, stream>>>(W_mlp1, wW, 16777216/8);
    gemm_bt<1><<<dim3(1024), gblk, 0, stream>>>(h, D_MODEL, wW, m1, nullptr, 4*D_MODEL, D_MODEL, 32);
    f2b_kernel<<<dim3(8192), blk, 0, stream>>>(W_mlp2, wW, 16777216/8);
    gemm_bt<2><<<dim3(256), gblk, 0, stream>>>(m1, 4*D_MODEL, wW, out, x2, D_MODEL, 4*D_MODEL, 8);
}